// Round 2
// 2611.368 us; speedup vs baseline: 1.6910x; 1.6910x over previous
//
#include <hip/hip_runtime.h>
#include <hip/hip_bf16.h>

typedef __attribute__((ext_vector_type(8))) short short8;
typedef __attribute__((ext_vector_type(4))) float f32x4;

#define S_ 64
#define B_ 64
#define H_ 1024
#define E_ 512
#define V_ 10000
#define M_ 4096          // S_*B_
#define VPAD 10048       // V rounded up to 64
#define NBLK 64

__device__ __forceinline__ float sigmoidf_(float x) {
  return 1.0f / (1.0f + __expf(-x));
}

// ---- fast device-scope grid barrier --------------------------------------------------
// Arrival: each block release-stores its own flag word (no RMW serialization).
// Detection: block 0 wave 0 polls all 64 flags in parallel (one load per lane),
// then release-stores gen. Others poll gen (relaxed) + acquire fence.
// Flags/gen never reset; idx increments by 1 per call, uniform across blocks.
__device__ __forceinline__ void gbar(int* flags, int* gen, int idx) {
  __syncthreads();
  if (blockIdx.x == 0) {
    if (threadIdx.x < 64) {
      int lane = threadIdx.x;
      if (lane == 0)
        __hip_atomic_store(&flags[0], idx, __ATOMIC_RELEASE, __HIP_MEMORY_SCOPE_AGENT);
      for (;;) {
        int v = __hip_atomic_load(&flags[lane], __ATOMIC_RELAXED, __HIP_MEMORY_SCOPE_AGENT);
        if (__all(v >= idx)) break;
        __builtin_amdgcn_s_sleep(1);
      }
      __builtin_amdgcn_fence(__ATOMIC_ACQUIRE, "agent");
      if (lane == 0)
        __hip_atomic_store(gen, idx, __ATOMIC_RELEASE, __HIP_MEMORY_SCOPE_AGENT);
    }
  } else {
    if (threadIdx.x == 0) {
      __hip_atomic_store(&flags[blockIdx.x], idx, __ATOMIC_RELEASE, __HIP_MEMORY_SCOPE_AGENT);
      while (__hip_atomic_load(gen, __ATOMIC_RELAXED, __HIP_MEMORY_SCOPE_AGENT) < idx)
        __builtin_amdgcn_s_sleep(1);
      __builtin_amdgcn_fence(__ATOMIC_ACQUIRE, "agent");
    }
  }
  __syncthreads();
}

// ---------------- bias concat: b0cat = [br0,bz0,bh0], b1cat = [br1,bz1,bh1] -------------
__global__ void bias_concat(const float* br0, const float* bz0, const float* bh0,
                            const float* br1, const float* bz1, const float* bh1,
                            float* b0cat, float* b1cat) {
  int i = blockIdx.x * 256 + threadIdx.x;   // 0..3071
  if (i >= 3072) return;
  if (i < 1024)       { b0cat[i] = br0[i];        b1cat[i] = br1[i]; }
  else if (i < 2048)  { b0cat[i] = bz0[i - 1024]; b1cat[i] = bz1[i - 1024]; }
  else                { b0cat[i] = bh0[i - 2048]; b1cat[i] = bh1[i - 2048]; }
}

// ---------------- transpose + cast: dst[c*R + r] = bf16(src[r*C + c]) -------------------
__global__ void transpose_cast(const float* __restrict__ src, __hip_bfloat16* __restrict__ dst,
                               int R, int C) {
  __shared__ float tile[32][33];
  int c0 = blockIdx.x * 32, r0 = blockIdx.y * 32;
  int tx = threadIdx.x & 31, ty = threadIdx.x >> 5;   // 32 x 8
#pragma unroll
  for (int i = 0; i < 4; ++i) {
    int r = r0 + ty + i * 8;
    int c = c0 + tx;
    if (r < R && c < C) tile[ty + i * 8][tx] = src[(size_t)r * C + c];
  }
  __syncthreads();
#pragma unroll
  for (int i = 0; i < 4; ++i) {
    int c = c0 + ty + i * 8;
    int r = r0 + tx;
    if (c < C && r < R) dst[(size_t)c * R + r] = __float2bfloat16(tile[tx][ty + i * 8]);
  }
}

// ---------------- embedding gather + cast to bf16: X0[i][e] = emb[tok[i]][e] ------------
__global__ void embed_cast(const int* __restrict__ inputs, const float* __restrict__ emb,
                           __hip_bfloat16* __restrict__ X0) {
  int idx = blockIdx.x * 256 + threadIdx.x;  // over 4096 * 128 float4 groups
  int i = idx >> 7;
  int e4 = idx & 127;
  int tok = inputs[i];
  const float4* src = (const float4*)(emb + (size_t)tok * E_);
  float4 v = src[e4];
  __hip_bfloat16* dst = X0 + (size_t)i * E_ + e4 * 4;
  dst[0] = __float2bfloat16(v.x);
  dst[1] = __float2bfloat16(v.y);
  dst[2] = __float2bfloat16(v.z);
  dst[3] = __float2bfloat16(v.w);
}

// ---------------- generic bf16 MFMA GEMM: C = act(A[M,K] @ BT[N,K]^T + bias) ------------
// grid = (ceil(N/64), M/64), block = 256 (4 waves, each a 32x32 quadrant of the 64x64 tile)
__global__ __launch_bounds__(256) void gemm_bf16(
    const __hip_bfloat16* __restrict__ A, const __hip_bfloat16* __restrict__ BT,
    const float* __restrict__ bias, void* __restrict__ C,
    int M, int N, int K, int act, int out_bf16) {
  __shared__ unsigned short Al[64 * 72];
  __shared__ unsigned short Bl[64 * 72];
  const int m0 = blockIdx.y * 64, n0 = blockIdx.x * 64;
  const int tid = threadIdx.x;
  const int wave = tid >> 6, lane = tid & 63;
  const int quad = lane >> 4, lr = lane & 15;
  const int wm = (wave >> 1) * 32, wn = (wave & 1) * 32;
  const int srow = tid >> 2, scol = (tid & 3) << 4;

  f32x4 acc[2][2];
#pragma unroll
  for (int a = 0; a < 2; ++a)
#pragma unroll
    for (int b = 0; b < 2; ++b) acc[a][b] = (f32x4){0.f, 0.f, 0.f, 0.f};

  const __hip_bfloat16* Ag = A + (size_t)(m0 + srow) * K + scol;
  const __hip_bfloat16* Bg = BT + (size_t)(n0 + srow) * K + scol;

  for (int kb = 0; kb < K; kb += 64) {
    short8 a0 = *(const short8*)(Ag + kb);
    short8 a1 = *(const short8*)(Ag + kb + 8);
    short8 b0 = *(const short8*)(Bg + kb);
    short8 b1 = *(const short8*)(Bg + kb + 8);
    *(short8*)&Al[srow * 72 + scol] = a0;
    *(short8*)&Al[srow * 72 + scol + 8] = a1;
    *(short8*)&Bl[srow * 72 + scol] = b0;
    *(short8*)&Bl[srow * 72 + scol + 8] = b1;
    __syncthreads();
#pragma unroll
    for (int k2 = 0; k2 < 64; k2 += 32) {
      short8 af0 = *(const short8*)&Al[(wm + lr) * 72 + k2 + quad * 8];
      short8 af1 = *(const short8*)&Al[(wm + 16 + lr) * 72 + k2 + quad * 8];
      short8 bf0 = *(const short8*)&Bl[(wn + lr) * 72 + k2 + quad * 8];
      short8 bf1 = *(const short8*)&Bl[(wn + 16 + lr) * 72 + k2 + quad * 8];
      acc[0][0] = __builtin_amdgcn_mfma_f32_16x16x32_bf16(af0, bf0, acc[0][0], 0, 0, 0);
      acc[0][1] = __builtin_amdgcn_mfma_f32_16x16x32_bf16(af0, bf1, acc[0][1], 0, 0, 0);
      acc[1][0] = __builtin_amdgcn_mfma_f32_16x16x32_bf16(af1, bf0, acc[1][0], 0, 0, 0);
      acc[1][1] = __builtin_amdgcn_mfma_f32_16x16x32_bf16(af1, bf1, acc[1][1], 0, 0, 0);
    }
    __syncthreads();
  }

#pragma unroll
  for (int mi = 0; mi < 2; ++mi)
#pragma unroll
    for (int ni = 0; ni < 2; ++ni) {
      int n = n0 + wn + ni * 16 + lr;
      if (n >= N) continue;
      float bv = bias ? bias[n] : 0.f;
#pragma unroll
      for (int r = 0; r < 4; ++r) {
        int m = m0 + wm + mi * 16 + quad * 4 + r;
        float v = acc[mi][ni][r] + bv;
        if (act) v = sigmoidf_(v);
        if (out_bf16) ((__hip_bfloat16*)C)[(size_t)m * N + n] = __float2bfloat16(v);
        else          ((float*)C)[(size_t)m * N + n] = v;
      }
    }
}

// ---------------- cooperative GRU recurrence for one layer ------------------------------
// G:   [4096, 3072] fp32 pre-activation x-part (+bias), cols (r, z, hh)
// WT:  [3072, 1024] bf16 transposed h-part weights, rows (r, z, hh)
// 64 blocks x 256 threads. Block b owns output columns [16b, 16b+16) of ALL THREE gates,
// so z and h for those columns live in registers across phases (no z_buf / h_state).
// Weight slices (3 x 16 rows x 1024) are staged ONCE into LDS (immune to the barrier's
// L2 invalidation); the per-step k-loops read only h_bf / rh_bf from global.
__global__ __launch_bounds__(256, 1) void gru_recurrent(
    const float* __restrict__ G, const __hip_bfloat16* __restrict__ WT,
    const float* __restrict__ init_h,
    __hip_bfloat16* __restrict__ h_bf, __hip_bfloat16* __restrict__ rh_bf,
    __hip_bfloat16* __restrict__ Hseq, float* __restrict__ h_final,
    int* __restrict__ bar_flags, int* __restrict__ bar_gen) {
  // 48 rows x (1024 + 8 pad) shorts = 99072 B. Pad of 16 B/row gives uniform
  // bank-group spread for the strided ds_read_b128 pattern below.
  __shared__ unsigned short Wl[48 * 1032];

  const int bid = blockIdx.x;
  const int tid = threadIdx.x;
  const int wave = tid >> 6, lane = tid & 63;
  const int quad = lane >> 4, lr = lane & 15;
  const int nb = bid * 16;                      // owned column base

  // ---- stage weight slices into LDS (once): seg s holds WT rows [s*1024+nb, +16) ----
  // 48 rows x 128 chunks of 8 shorts (FULL 1024-short rows; round-1 bug was c&63).
  for (int c = tid; c < 48 * 128; c += 256) {
    int row = c >> 7;            // 0..47
    int col16 = c & 127;         // 16B chunk index, 0..127
    int seg = row >> 4, srow = row & 15;
    short8 v = *(const short8*)(WT + (size_t)(seg * 1024 + nb + srow) * H_ + col16 * 8);
    *(short8*)&Wl[row * 1032 + col16 * 8] = v;
  }

  // ---- init: h for owned columns lives in registers; publish bf16 copy globally ----
  float hreg[4], zreg[4];
#pragma unroll
  for (int r = 0; r < 4; ++r) {
    int mm = wave * 16 + quad * 4 + r;
    float v = init_h[mm * H_ + nb + lr];
    hreg[r] = v;
    zreg[r] = 0.f;
    h_bf[mm * H_ + nb + lr] = __float2bfloat16(v);
  }
  int bidx = 1;
  gbar(bar_flags, bar_gen, bidx++);

  for (int t = 0; t < S_; ++t) {
    // G prefetch for all three gates of this step (HBM latency hides under phase A)
    float g0[4], g1[4], gh[4];
#pragma unroll
    for (int r = 0; r < 4; ++r) {
      int mm = wave * 16 + quad * 4 + r;
      const float* gp = G + (size_t)(t * B_ + mm) * 3072 + nb + lr;
      g0[r] = gp[0];
      g1[r] = gp[1024];
      gh[r] = gp[2048];
    }

    // ---- phase A: r = sigmoid(Gr + h@Wr), z = sigmoid(Gz + h@Wz) for owned cols ----
    {
      const int am = wave * 16 + lr;
      const __hip_bfloat16* ap = h_bf + (size_t)am * H_ + quad * 8;
      short8 areg[32];
#pragma unroll
      for (int kk = 0; kk < 32; ++kk) areg[kk] = *(const short8*)(ap + kk * 32);
      f32x4 acc0 = (f32x4){0.f, 0.f, 0.f, 0.f};
      f32x4 acc1 = (f32x4){0.f, 0.f, 0.f, 0.f};
#pragma unroll
      for (int kk = 0; kk < 32; ++kk) {
        short8 b0 = *(const short8*)&Wl[lr * 1032 + quad * 8 + kk * 32];
        short8 b1 = *(const short8*)&Wl[(16 + lr) * 1032 + quad * 8 + kk * 32];
        acc0 = __builtin_amdgcn_mfma_f32_16x16x32_bf16(areg[kk], b0, acc0, 0, 0, 0);
        acc1 = __builtin_amdgcn_mfma_f32_16x16x32_bf16(areg[kk], b1, acc1, 0, 0, 0);
      }
#pragma unroll
      for (int r = 0; r < 4; ++r) {
        int mm = wave * 16 + quad * 4 + r;
        float rv = sigmoidf_(acc0[r] + g0[r]);
        zreg[r] = sigmoidf_(acc1[r] + g1[r]);
        rh_bf[mm * H_ + nb + lr] = __float2bfloat16(rv * hreg[r]);
      }
    }
    gbar(bar_flags, bar_gen, bidx++);

    // ---- phase B: hh = sigmoid(Gh + (r*h)@Wh); h = h + z*(hh - h) for owned cols ----
    {
      const int am = wave * 16 + lr;
      const __hip_bfloat16* ap = rh_bf + (size_t)am * H_ + quad * 8;
      short8 areg[32];
#pragma unroll
      for (int kk = 0; kk < 32; ++kk) areg[kk] = *(const short8*)(ap + kk * 32);
      f32x4 acc = (f32x4){0.f, 0.f, 0.f, 0.f};
#pragma unroll
      for (int kk = 0; kk < 32; ++kk) {
        short8 b = *(const short8*)&Wl[(32 + lr) * 1032 + quad * 8 + kk * 32];
        acc = __builtin_amdgcn_mfma_f32_16x16x32_bf16(areg[kk], b, acc, 0, 0, 0);
      }
#pragma unroll
      for (int r = 0; r < 4; ++r) {
        int mm = wave * 16 + quad * 4 + r;
        int nn = nb + lr;
        float hh = sigmoidf_(acc[r] + gh[r]);
        float hn = hreg[r] + zreg[r] * (hh - hreg[r]);
        hreg[r] = hn;
        __hip_bfloat16 hb = __float2bfloat16(hn);
        h_bf[mm * H_ + nn] = hb;
        Hseq[(size_t)(t * B_ + mm) * H_ + nn] = hb;
        if (t == S_ - 1) h_final[mm * H_ + nn] = hn;
      }
    }
    gbar(bar_flags, bar_gen, bidx++);
  }
}

// ---------------------------------- host launcher ---------------------------------------
extern "C" void kernel_launch(void* const* d_in, const int* in_sizes, int n_in,
                              void* d_out, int out_size, void* d_ws, size_t ws_size,
                              hipStream_t stream) {
  const int*   inputs      = (const int*)d_in[0];
  const float* init_hidden = (const float*)d_in[1];
  const float* emb         = (const float*)d_in[2];
  const float* Wr0 = (const float*)d_in[3];
  const float* Wz0 = (const float*)d_in[4];
  const float* Wh0 = (const float*)d_in[5];
  const float* br0 = (const float*)d_in[6];
  const float* bz0 = (const float*)d_in[7];
  const float* bh0 = (const float*)d_in[8];
  const float* Wr1 = (const float*)d_in[9];
  const float* Wz1 = (const float*)d_in[10];
  const float* Wh1 = (const float*)d_in[11];
  const float* br1 = (const float*)d_in[12];
  const float* bz1 = (const float*)d_in[13];
  const float* bh1 = (const float*)d_in[14];
  const float* Wfc0 = (const float*)d_in[15];
  const float* bfc0 = (const float*)d_in[16];
  const float* Wout = (const float*)d_in[17];
  const float* bout = (const float*)d_in[18];
  float* out = (float*)d_out;

  // -------- workspace layout --------
  char* ws = (char*)d_ws;
  size_t off = 0;
  auto alloc = [&](size_t bytes) -> char* {
    char* p = ws + off;
    off = (off + bytes + 255) & ~(size_t)255;
    return p;
  };
  int* bar = (int*)alloc(2048);  // barrier state: 2 x {flags[64], gen}
  __hip_bfloat16* W0xT  = (__hip_bfloat16*)alloc((size_t)3072 * E_ * 2);
  __hip_bfloat16* W0hT  = (__hip_bfloat16*)alloc((size_t)3072 * H_ * 2);
  __hip_bfloat16* WfcT  = (__hip_bfloat16*)alloc((size_t)H_ * H_ * 2);
  __hip_bfloat16* W1xT  = (__hip_bfloat16*)alloc((size_t)3072 * H_ * 2);
  __hip_bfloat16* W1hT  = (__hip_bfloat16*)alloc((size_t)3072 * H_ * 2);
  __hip_bfloat16* WoutT = (__hip_bfloat16*)alloc((size_t)VPAD * H_ * 2);
  float* b0cat = (float*)alloc(3072 * 4);
  float* b1cat = (float*)alloc(3072 * 4);
  __hip_bfloat16* X0    = (__hip_bfloat16*)alloc((size_t)M_ * E_ * 2);
  float* G              = (float*)alloc((size_t)M_ * 3072 * 4);
  __hip_bfloat16* Hseq0 = (__hip_bfloat16*)alloc((size_t)M_ * H_ * 2);
  __hip_bfloat16* X1    = (__hip_bfloat16*)alloc((size_t)M_ * H_ * 2);
  __hip_bfloat16* Hseq1 = (__hip_bfloat16*)alloc((size_t)M_ * H_ * 2);
  __hip_bfloat16* hb0 = (__hip_bfloat16*)alloc((size_t)B_ * H_ * 2);
  __hip_bfloat16* hb1 = (__hip_bfloat16*)alloc((size_t)B_ * H_ * 2);
  __hip_bfloat16* rh  = (__hip_bfloat16*)alloc((size_t)B_ * H_ * 2);
  (void)ws_size; (void)n_in; (void)in_sizes; (void)out_size;

  // zero the barrier state (workspace is poisoned 0xAA before every launch)
  hipMemsetAsync(bar, 0, 2048, stream);

  // -------- prep: biases, transposed bf16 weights, embedding --------
  hipLaunchKernelGGL(bias_concat, dim3(12), dim3(256), 0, stream,
                     br0, bz0, bh0, br1, bz1, bh1, b0cat, b1cat);

  auto tp = [&](const float* src, __hip_bfloat16* dst, int R, int C) {
    hipLaunchKernelGGL(transpose_cast, dim3((C + 31) / 32, (R + 31) / 32), dim3(256), 0,
                       stream, src, dst, R, C);
  };
  // layer 0 x-part [E,H] -> [3H, E]
  tp(Wr0,            W0xT,                E_, H_);
  tp(Wz0,            W0xT + 1024 * E_,    E_, H_);
  tp(Wh0,            W0xT + 2048 * E_,    E_, H_);
  // layer 0 h-part
  tp(Wr0 + (size_t)E_ * H_, W0hT,               H_, H_);
  tp(Wz0 + (size_t)E_ * H_, W0hT + 1024 * H_,   H_, H_);
  tp(Wh0 + (size_t)E_ * H_, W0hT + 2048 * H_,   H_, H_);
  // fc
  tp(Wfc0, WfcT, H_, H_);
  // layer 1 x-part
  tp(Wr1,            W1xT,                H_, H_);
  tp(Wz1,            W1xT + 1024 * H_,    H_, H_);
  tp(Wh1,            W1xT + 2048 * H_,    H_, H_);
  // layer 1 h-part
  tp(Wr1 + (size_t)H_ * H_, W1hT,               H_, H_);
  tp(Wz1 + (size_t)H_ * H_, W1hT + 1024 * H_,   H_, H_);
  tp(Wh1 + (size_t)H_ * H_, W1hT + 2048 * H_,   H_, H_);
  // out projection [H,V] -> [Vpad, H] (rows >= V left as poison, guarded at GEMM store)
  tp(Wout, WoutT, H_, V_);

  hipLaunchKernelGGL(embed_cast, dim3(M_ * (E_ / 4) / 256), dim3(256), 0, stream,
                     inputs, emb, X0);

  // -------- G0 = X0 @ W0x + b0cat  (fp32 [4096,3072]) --------
  hipLaunchKernelGGL(gemm_bf16, dim3(3072 / 64, M_ / 64), dim3(256), 0, stream,
                     X0, W0xT, b0cat, (void*)G, M_, 3072, E_, 0, 0);

  // -------- layer 0 recurrence --------
  {
    const float* Gp = G; const __hip_bfloat16* WTp = W0hT;
    const float* inith = init_hidden;                 // layer 0 slice
    __hip_bfloat16* hbp = hb0; __hip_bfloat16* rhp = rh;
    __hip_bfloat16* Hsp = Hseq0;
    float* hfin = out + (size_t)M_ * V_;              // h_final layer 0
    int* f0 = bar; int* g0 = bar + 64;
    void* kargs[] = {(void*)&Gp, (void*)&WTp, (void*)&inith, (void*)&hbp,
                     (void*)&rhp, (void*)&Hsp, (void*)&hfin,
                     (void*)&f0, (void*)&g0};
    hipLaunchCooperativeKernel((const void*)gru_recurrent, dim3(NBLK), dim3(256),
                               kargs, 0, stream);
  }

  // -------- X1 = sigmoid(Hseq0 @ Wfc + bfc)  (bf16 [4096,1024]) --------
  hipLaunchKernelGGL(gemm_bf16, dim3(H_ / 64, M_ / 64), dim3(256), 0, stream,
                     Hseq0, WfcT, bfc0, (void*)X1, M_, H_, H_, 1, 1);

  // -------- G1 = X1 @ W1x + b1cat  (fp32 [4096,3072]) --------
  hipLaunchKernelGGL(gemm_bf16, dim3(3072 / 64, M_ / 64), dim3(256), 0, stream,
                     X1, W1xT, b1cat, (void*)G, M_, 3072, H_, 0, 0);

  // -------- layer 1 recurrence --------
  {
    const float* Gp = G; const __hip_bfloat16* WTp = W1hT;
    const float* inith = init_hidden + (size_t)B_ * H_;   // layer 1 slice
    __hip_bfloat16* hbp = hb1; __hip_bfloat16* rhp = rh;
    __hip_bfloat16* Hsp = Hseq1;
    float* hfin = out + (size_t)M_ * V_ + (size_t)B_ * H_;  // h_final layer 1
    int* f1 = bar + 128; int* g1 = bar + 192;
    void* kargs[] = {(void*)&Gp, (void*)&WTp, (void*)&inith, (void*)&hbp,
                     (void*)&rhp, (void*)&Hsp, (void*)&hfin,
                     (void*)&f1, (void*)&g1};
    hipLaunchCooperativeKernel((const void*)gru_recurrent, dim3(NBLK), dim3(256),
                               kargs, 0, stream);
  }

  // -------- logits = Hseq1 @ Wout + bout  (fp32 [4096,10000] straight into d_out) -------
  hipLaunchKernelGGL(gemm_bf16, dim3(VPAD / 64, M_ / 64), dim3(256), 0, stream,
                     Hseq1, WoutT, bout, (void*)out, M_, V_, H_, 0, 0);
}

// Round 3
// 2525.091 us; speedup vs baseline: 1.7487x; 1.0342x over previous
//
#include <hip/hip_runtime.h>
#include <hip/hip_bf16.h>

typedef __attribute__((ext_vector_type(8))) short short8;
typedef __attribute__((ext_vector_type(4))) float f32x4;

#define S_ 64
#define B_ 64
#define H_ 1024
#define E_ 512
#define V_ 10000
#define M_ 4096          // S_*B_
#define VPAD 10048       // V rounded up to 64
#define NBLK 256         // 4 gangs x 64 blocks

__device__ __forceinline__ float sigmoidf_(float x) {
  return 1.0f / (1.0f + __expf(-x));
}

// ---- fast device-scope grid barrier (256 blocks) -------------------------------------
// Arrival: each block release-stores its own flag word (no RMW serialization).
// Detection: block 0 wave 0 polls all 256 flags (4 per lane), then release-stores gen.
// Others poll gen (relaxed) + acquire fence. Flags/gen never reset; idx increments.
__device__ __forceinline__ void gbar(int* flags, int* gen, int idx) {
  __syncthreads();
  if (blockIdx.x == 0) {
    if (threadIdx.x < 64) {
      int lane = threadIdx.x;
      if (lane == 0)
        __hip_atomic_store(&flags[0], idx, __ATOMIC_RELEASE, __HIP_MEMORY_SCOPE_AGENT);
      for (;;) {
        int v0 = __hip_atomic_load(&flags[lane],       __ATOMIC_RELAXED, __HIP_MEMORY_SCOPE_AGENT);
        int v1 = __hip_atomic_load(&flags[lane + 64],  __ATOMIC_RELAXED, __HIP_MEMORY_SCOPE_AGENT);
        int v2 = __hip_atomic_load(&flags[lane + 128], __ATOMIC_RELAXED, __HIP_MEMORY_SCOPE_AGENT);
        int v3 = __hip_atomic_load(&flags[lane + 192], __ATOMIC_RELAXED, __HIP_MEMORY_SCOPE_AGENT);
        int mn = min(min(v0, v1), min(v2, v3));
        if (__all(mn >= idx)) break;
        __builtin_amdgcn_s_sleep(1);
      }
      __builtin_amdgcn_fence(__ATOMIC_ACQUIRE, "agent");
      if (lane == 0)
        __hip_atomic_store(gen, idx, __ATOMIC_RELEASE, __HIP_MEMORY_SCOPE_AGENT);
    }
  } else {
    if (threadIdx.x == 0) {
      __hip_atomic_store(&flags[blockIdx.x], idx, __ATOMIC_RELEASE, __HIP_MEMORY_SCOPE_AGENT);
      while (__hip_atomic_load(gen, __ATOMIC_RELAXED, __HIP_MEMORY_SCOPE_AGENT) < idx)
        __builtin_amdgcn_s_sleep(1);
      __builtin_amdgcn_fence(__ATOMIC_ACQUIRE, "agent");
    }
  }
  __syncthreads();
}

// ---------------- bias concat: b0cat = [br0,bz0,bh0], b1cat = [br1,bz1,bh1] -------------
__global__ void bias_concat(const float* br0, const float* bz0, const float* bh0,
                            const float* br1, const float* bz1, const float* bh1,
                            float* b0cat, float* b1cat) {
  int i = blockIdx.x * 256 + threadIdx.x;   // 0..3071
  if (i >= 3072) return;
  if (i < 1024)       { b0cat[i] = br0[i];        b1cat[i] = br1[i]; }
  else if (i < 2048)  { b0cat[i] = bz0[i - 1024]; b1cat[i] = bz1[i - 1024]; }
  else                { b0cat[i] = bh0[i - 2048]; b1cat[i] = bh1[i - 2048]; }
}

// ---------------- transpose + cast: dst[c*R + r] = bf16(src[r*C + c]) -------------------
__global__ void transpose_cast(const float* __restrict__ src, __hip_bfloat16* __restrict__ dst,
                               int R, int C) {
  __shared__ float tile[32][33];
  int c0 = blockIdx.x * 32, r0 = blockIdx.y * 32;
  int tx = threadIdx.x & 31, ty = threadIdx.x >> 5;   // 32 x 8
#pragma unroll
  for (int i = 0; i < 4; ++i) {
    int r = r0 + ty + i * 8;
    int c = c0 + tx;
    if (r < R && c < C) tile[ty + i * 8][tx] = src[(size_t)r * C + c];
  }
  __syncthreads();
#pragma unroll
  for (int i = 0; i < 4; ++i) {
    int c = c0 + ty + i * 8;
    int r = r0 + tx;
    if (c < C && r < R) dst[(size_t)c * R + r] = __float2bfloat16(tile[tx][ty + i * 8]);
  }
}

// ---------------- embedding gather + cast to bf16: X0[i][e] = emb[tok[i]][e] ------------
__global__ void embed_cast(const int* __restrict__ inputs, const float* __restrict__ emb,
                           __hip_bfloat16* __restrict__ X0) {
  int idx = blockIdx.x * 256 + threadIdx.x;  // over 4096 * 128 float4 groups
  int i = idx >> 7;
  int e4 = idx & 127;
  int tok = inputs[i];
  const float4* src = (const float4*)(emb + (size_t)tok * E_);
  float4 v = src[e4];
  __hip_bfloat16* dst = X0 + (size_t)i * E_ + e4 * 4;
  dst[0] = __float2bfloat16(v.x);
  dst[1] = __float2bfloat16(v.y);
  dst[2] = __float2bfloat16(v.z);
  dst[3] = __float2bfloat16(v.w);
}

// ---------------- generic bf16 MFMA GEMM: C = act(A[M,K] @ BT[N,K]^T + bias) ------------
// grid = (ceil(N/64), M/64), block = 256 (4 waves, each a 32x32 quadrant of the 64x64 tile)
__global__ __launch_bounds__(256) void gemm_bf16(
    const __hip_bfloat16* __restrict__ A, const __hip_bfloat16* __restrict__ BT,
    const float* __restrict__ bias, void* __restrict__ C,
    int M, int N, int K, int act, int out_bf16) {
  __shared__ unsigned short Al[64 * 72];
  __shared__ unsigned short Bl[64 * 72];
  const int m0 = blockIdx.y * 64, n0 = blockIdx.x * 64;
  const int tid = threadIdx.x;
  const int wave = tid >> 6, lane = tid & 63;
  const int quad = lane >> 4, lr = lane & 15;
  const int wm = (wave >> 1) * 32, wn = (wave & 1) * 32;
  const int srow = tid >> 2, scol = (tid & 3) << 4;

  f32x4 acc[2][2];
#pragma unroll
  for (int a = 0; a < 2; ++a)
#pragma unroll
    for (int b = 0; b < 2; ++b) acc[a][b] = (f32x4){0.f, 0.f, 0.f, 0.f};

  const __hip_bfloat16* Ag = A + (size_t)(m0 + srow) * K + scol;
  const __hip_bfloat16* Bg = BT + (size_t)(n0 + srow) * K + scol;

  for (int kb = 0; kb < K; kb += 64) {
    short8 a0 = *(const short8*)(Ag + kb);
    short8 a1 = *(const short8*)(Ag + kb + 8);
    short8 b0 = *(const short8*)(Bg + kb);
    short8 b1 = *(const short8*)(Bg + kb + 8);
    *(short8*)&Al[srow * 72 + scol] = a0;
    *(short8*)&Al[srow * 72 + scol + 8] = a1;
    *(short8*)&Bl[srow * 72 + scol] = b0;
    *(short8*)&Bl[srow * 72 + scol + 8] = b1;
    __syncthreads();
#pragma unroll
    for (int k2 = 0; k2 < 64; k2 += 32) {
      short8 af0 = *(const short8*)&Al[(wm + lr) * 72 + k2 + quad * 8];
      short8 af1 = *(const short8*)&Al[(wm + 16 + lr) * 72 + k2 + quad * 8];
      short8 bf0 = *(const short8*)&Bl[(wn + lr) * 72 + k2 + quad * 8];
      short8 bf1 = *(const short8*)&Bl[(wn + 16 + lr) * 72 + k2 + quad * 8];
      acc[0][0] = __builtin_amdgcn_mfma_f32_16x16x32_bf16(af0, bf0, acc[0][0], 0, 0, 0);
      acc[0][1] = __builtin_amdgcn_mfma_f32_16x16x32_bf16(af0, bf1, acc[0][1], 0, 0, 0);
      acc[1][0] = __builtin_amdgcn_mfma_f32_16x16x32_bf16(af1, bf0, acc[1][0], 0, 0, 0);
      acc[1][1] = __builtin_amdgcn_mfma_f32_16x16x32_bf16(af1, bf1, acc[1][1], 0, 0, 0);
    }
    __syncthreads();
  }

#pragma unroll
  for (int mi = 0; mi < 2; ++mi)
#pragma unroll
    for (int ni = 0; ni < 2; ++ni) {
      int n = n0 + wn + ni * 16 + lr;
      if (n >= N) continue;
      float bv = bias ? bias[n] : 0.f;
#pragma unroll
      for (int r = 0; r < 4; ++r) {
        int m = m0 + wm + mi * 16 + quad * 4 + r;
        float v = acc[mi][ni][r] + bv;
        if (act) v = sigmoidf_(v);
        if (out_bf16) ((__hip_bfloat16*)C)[(size_t)m * N + n] = __float2bfloat16(v);
        else          ((float*)C)[(size_t)m * N + n] = v;
      }
    }
}

// ---------------- fused 2-layer GRU pipeline -------------------------------------------
// 4 gangs x 64 blocks, software-pipelined on a global tick (2 ticks per timestep):
//   gang 0 (blocks   0.. 63): layer-0 recurrence, W0h in LDS, cols gid*16..+16
//       phase A at tick 2t, phase B at tick 2t+1  ->  h0_t in h0b after tick 2t+1
//   gang 1 (blocks  64..127): x1_t = sigmoid(h0_t @ Wfc + bfc) at tick 2t+2 -> x1b
//   gang 2 (blocks 128..191): g1_t = x1_t @ W1x + b1cat        at tick 2t+3 -> g1buf
//   gang 3 (blocks 192..255): layer-1 recurrence, W1h in LDS
//       phase A at tick 2t+4, phase B at tick 2t+5 -> h1b, Hseq1, h_final
// x1b / g1buf are single-buffered: written in tick k, consumed into registers in tick
// k+1 (drained by the barrier's vmcnt(0)), overwritten earliest in tick k+2.
// Total ticks: 2*64 + 4 = 132; one gbar per tick + 1 init barrier.
__global__ __launch_bounds__(256, 1) void gru_fused(
    const float* __restrict__ G0,
    const __hip_bfloat16* __restrict__ W0hT, const __hip_bfloat16* __restrict__ WfcT,
    const __hip_bfloat16* __restrict__ W1xT, const __hip_bfloat16* __restrict__ W1hT,
    const float* __restrict__ bfc, const float* __restrict__ b1cat,
    const float* __restrict__ init_h,
    __hip_bfloat16* __restrict__ h0b, __hip_bfloat16* __restrict__ rh0,
    __hip_bfloat16* __restrict__ h1b, __hip_bfloat16* __restrict__ rh1,
    __hip_bfloat16* __restrict__ x1b, float* __restrict__ g1buf,
    __hip_bfloat16* __restrict__ Hseq1, float* __restrict__ hfin,
    int* __restrict__ bar_flags, int* __restrict__ bar_gen) {
  // 48 rows x (1024 + 8 pad) shorts = 99072 B (max over gangs; gang 1 uses 16 rows)
  __shared__ unsigned short Wl[48 * 1032];

  const int bid = blockIdx.x;
  const int gang = bid >> 6;      // 0:L0  1:FC  2:G1  3:L1
  const int gid = bid & 63;
  const int tid = threadIdx.x;
  const int wave = tid >> 6, lane = tid & 63;
  const int quad = lane >> 4, lr = lane & 15;

  // ---- stage this gang's weight slice into LDS (once) ----
  if (gang == 0 || gang == 3) {
    const __hip_bfloat16* WT = (gang == 0) ? W0hT : W1hT;
    const int nb = gid * 16;
    for (int c = tid; c < 48 * 128; c += 256) {
      int row = c >> 7, col = c & 127;          // row 0..47, 16B chunk 0..127
      int seg = row >> 4, srow = row & 15;      // gate segment, row within
      short8 v = *(const short8*)(WT + (size_t)(seg * 1024 + nb + srow) * H_ + col * 8);
      *(short8*)&Wl[row * 1032 + col * 8] = v;
    }
  } else if (gang == 1) {
    const int nb = gid * 16;
    for (int c = tid; c < 16 * 128; c += 256) {
      int row = c >> 7, col = c & 127;
      short8 v = *(const short8*)(WfcT + (size_t)(nb + row) * H_ + col * 8);
      *(short8*)&Wl[row * 1032 + col * 8] = v;
    }
  } else {
    const int nb = gid * 48;
    for (int c = tid; c < 48 * 128; c += 256) {
      int row = c >> 7, col = c & 127;
      short8 v = *(const short8*)(W1xT + (size_t)(nb + row) * H_ + col * 8);
      *(short8*)&Wl[row * 1032 + col * 8] = v;
    }
  }

  // ---- per-gang persistent register state ----
  float hreg[4], zreg[4], ghp[4];
  float bias0 = 0.f, bias1 = 0.f, bias2 = 0.f;
  if (gang == 0 || gang == 3) {
    const float* ih = init_h + (gang == 3 ? B_ * H_ : 0);
    __hip_bfloat16* hb = (gang == 0) ? h0b : h1b;
    const int nb = gid * 16;
#pragma unroll
    for (int r = 0; r < 4; ++r) {
      int mm = wave * 16 + quad * 4 + r;
      float v = ih[mm * H_ + nb + lr];
      hreg[r] = v; zreg[r] = 0.f; ghp[r] = 0.f;
      hb[mm * H_ + nb + lr] = __float2bfloat16(v);
    }
  } else if (gang == 1) {
    bias0 = bfc[gid * 16 + lr];
  } else {
    const int nb = gid * 48;
    bias0 = b1cat[nb + lr];
    bias1 = b1cat[nb + 16 + lr];
    bias2 = b1cat[nb + 32 + lr];
  }

  int bidx = 1;
  gbar(bar_flags, bar_gen, bidx++);   // init: h0b/h1b published

  for (int k = 0; k < 132; ++k) {
    if (gang == 0) {
      if (k < 128) {
        const int nb = gid * 16;
        const int am = wave * 16 + lr;
        const int t = k >> 1;
        if (!(k & 1)) {
          // ---- L0 phase A: r,z for owned cols; write rh0 ----
          float g0v[4], g1v[4];
#pragma unroll
          for (int r = 0; r < 4; ++r) {
            int mm = wave * 16 + quad * 4 + r;
            const float* gp = G0 + (size_t)(t * B_ + mm) * 3072 + nb + lr;
            g0v[r] = gp[0]; g1v[r] = gp[1024]; ghp[r] = gp[2048];
          }
          const __hip_bfloat16* ap = h0b + (size_t)am * H_ + quad * 8;
          short8 areg[32];
#pragma unroll
          for (int kk = 0; kk < 32; ++kk) areg[kk] = *(const short8*)(ap + kk * 32);
          f32x4 acc0 = (f32x4){0.f, 0.f, 0.f, 0.f};
          f32x4 acc1 = (f32x4){0.f, 0.f, 0.f, 0.f};
#pragma unroll
          for (int kk = 0; kk < 32; ++kk) {
            short8 b0 = *(const short8*)&Wl[lr * 1032 + quad * 8 + kk * 32];
            short8 b1 = *(const short8*)&Wl[(16 + lr) * 1032 + quad * 8 + kk * 32];
            acc0 = __builtin_amdgcn_mfma_f32_16x16x32_bf16(areg[kk], b0, acc0, 0, 0, 0);
            acc1 = __builtin_amdgcn_mfma_f32_16x16x32_bf16(areg[kk], b1, acc1, 0, 0, 0);
          }
#pragma unroll
          for (int r = 0; r < 4; ++r) {
            int mm = wave * 16 + quad * 4 + r;
            float rv = sigmoidf_(acc0[r] + g0v[r]);
            zreg[r] = sigmoidf_(acc1[r] + g1v[r]);
            rh0[mm * H_ + nb + lr] = __float2bfloat16(rv * hreg[r]);
          }
        } else {
          // ---- L0 phase B: hh; h update; publish h0b ----
          const __hip_bfloat16* ap = rh0 + (size_t)am * H_ + quad * 8;
          short8 areg[32];
#pragma unroll
          for (int kk = 0; kk < 32; ++kk) areg[kk] = *(const short8*)(ap + kk * 32);
          f32x4 acc = (f32x4){0.f, 0.f, 0.f, 0.f};
#pragma unroll
          for (int kk = 0; kk < 32; ++kk) {
            short8 b = *(const short8*)&Wl[(32 + lr) * 1032 + quad * 8 + kk * 32];
            acc = __builtin_amdgcn_mfma_f32_16x16x32_bf16(areg[kk], b, acc, 0, 0, 0);
          }
#pragma unroll
          for (int r = 0; r < 4; ++r) {
            int mm = wave * 16 + quad * 4 + r;
            int nn = nb + lr;
            float hh = sigmoidf_(acc[r] + ghp[r]);
            float hn = hreg[r] + zreg[r] * (hh - hreg[r]);
            hreg[r] = hn;
            h0b[mm * H_ + nn] = __float2bfloat16(hn);
            if (t == S_ - 1) hfin[mm * H_ + nn] = hn;
          }
        }
      }
    } else if (gang == 1) {
      // ---- FC: x1_t = sigmoid(h0_t @ Wfc + bfc), tick 2t+2 ----
      if (!(k & 1) && k >= 2 && k <= 128) {
        const int nb = gid * 16;
        const int am = wave * 16 + lr;
        const __hip_bfloat16* ap = h0b + (size_t)am * H_ + quad * 8;
        short8 areg[32];
#pragma unroll
        for (int kk = 0; kk < 32; ++kk) areg[kk] = *(const short8*)(ap + kk * 32);
        f32x4 acc = (f32x4){0.f, 0.f, 0.f, 0.f};
#pragma unroll
        for (int kk = 0; kk < 32; ++kk) {
          short8 b = *(const short8*)&Wl[lr * 1032 + quad * 8 + kk * 32];
          acc = __builtin_amdgcn_mfma_f32_16x16x32_bf16(areg[kk], b, acc, 0, 0, 0);
        }
#pragma unroll
        for (int r = 0; r < 4; ++r) {
          int mm = wave * 16 + quad * 4 + r;
          float v = sigmoidf_(acc[r] + bias0);
          x1b[mm * H_ + nb + lr] = __float2bfloat16(v);
        }
      }
    } else if (gang == 2) {
      // ---- G1: g1_t = x1_t @ W1x + b1cat (fp32, no act), tick 2t+3 ----
      if ((k & 1) && k >= 3 && k <= 129) {
        const int nb = gid * 48;
        const int am = wave * 16 + lr;
        const __hip_bfloat16* ap = x1b + (size_t)am * H_ + quad * 8;
        short8 areg[32];
#pragma unroll
        for (int kk = 0; kk < 32; ++kk) areg[kk] = *(const short8*)(ap + kk * 32);
        f32x4 a0 = (f32x4){0.f, 0.f, 0.f, 0.f};
        f32x4 a1 = (f32x4){0.f, 0.f, 0.f, 0.f};
        f32x4 a2 = (f32x4){0.f, 0.f, 0.f, 0.f};
#pragma unroll
        for (int kk = 0; kk < 32; ++kk) {
          short8 b0 = *(const short8*)&Wl[lr * 1032 + quad * 8 + kk * 32];
          short8 b1 = *(const short8*)&Wl[(16 + lr) * 1032 + quad * 8 + kk * 32];
          short8 b2 = *(const short8*)&Wl[(32 + lr) * 1032 + quad * 8 + kk * 32];
          a0 = __builtin_amdgcn_mfma_f32_16x16x32_bf16(areg[kk], b0, a0, 0, 0, 0);
          a1 = __builtin_amdgcn_mfma_f32_16x16x32_bf16(areg[kk], b1, a1, 0, 0, 0);
          a2 = __builtin_amdgcn_mfma_f32_16x16x32_bf16(areg[kk], b2, a2, 0, 0, 0);
        }
#pragma unroll
        for (int r = 0; r < 4; ++r) {
          int mm = wave * 16 + quad * 4 + r;
          float* gp = g1buf + (size_t)mm * 3072 + nb + lr;
          gp[0]  = a0[r] + bias0;
          gp[16] = a1[r] + bias1;
          gp[32] = a2[r] + bias2;
        }
      }
    } else {
      // ---- L1 recurrence (reads g1buf instead of a t-indexed G) ----
      if (k >= 4) {
        const int nb = gid * 16;
        const int am = wave * 16 + lr;
        if (!(k & 1)) {
          if (k <= 130) {
            // phase A
            float g0v[4], g1v[4];
#pragma unroll
            for (int r = 0; r < 4; ++r) {
              int mm = wave * 16 + quad * 4 + r;
              const float* gp = g1buf + (size_t)mm * 3072 + nb + lr;
              g0v[r] = gp[0]; g1v[r] = gp[1024]; ghp[r] = gp[2048];
            }
            const __hip_bfloat16* ap = h1b + (size_t)am * H_ + quad * 8;
            short8 areg[32];
#pragma unroll
            for (int kk = 0; kk < 32; ++kk) areg[kk] = *(const short8*)(ap + kk * 32);
            f32x4 acc0 = (f32x4){0.f, 0.f, 0.f, 0.f};
            f32x4 acc1 = (f32x4){0.f, 0.f, 0.f, 0.f};
#pragma unroll
            for (int kk = 0; kk < 32; ++kk) {
              short8 b0 = *(const short8*)&Wl[lr * 1032 + quad * 8 + kk * 32];
              short8 b1 = *(const short8*)&Wl[(16 + lr) * 1032 + quad * 8 + kk * 32];
              acc0 = __builtin_amdgcn_mfma_f32_16x16x32_bf16(areg[kk], b0, acc0, 0, 0, 0);
              acc1 = __builtin_amdgcn_mfma_f32_16x16x32_bf16(areg[kk], b1, acc1, 0, 0, 0);
            }
#pragma unroll
            for (int r = 0; r < 4; ++r) {
              int mm = wave * 16 + quad * 4 + r;
              float rv = sigmoidf_(acc0[r] + g0v[r]);
              zreg[r] = sigmoidf_(acc1[r] + g1v[r]);
              rh1[mm * H_ + nb + lr] = __float2bfloat16(rv * hreg[r]);
            }
          }
        } else {
          if (k <= 131) {
            // phase B
            const int t = (k - 5) >> 1;
            const __hip_bfloat16* ap = rh1 + (size_t)am * H_ + quad * 8;
            short8 areg[32];
#pragma unroll
            for (int kk = 0; kk < 32; ++kk) areg[kk] = *(const short8*)(ap + kk * 32);
            f32x4 acc = (f32x4){0.f, 0.f, 0.f, 0.f};
#pragma unroll
            for (int kk = 0; kk < 32; ++kk) {
              short8 b = *(const short8*)&Wl[(32 + lr) * 1032 + quad * 8 + kk * 32];
              acc = __builtin_amdgcn_mfma_f32_16x16x32_bf16(areg[kk], b, acc, 0, 0, 0);
            }
#pragma unroll
            for (int r = 0; r < 4; ++r) {
              int mm = wave * 16 + quad * 4 + r;
              int nn = nb + lr;
              float hh = sigmoidf_(acc[r] + ghp[r]);
              float hn = hreg[r] + zreg[r] * (hh - hreg[r]);
              hreg[r] = hn;
              __hip_bfloat16 hb = __float2bfloat16(hn);
              h1b[mm * H_ + nn] = hb;
              Hseq1[(size_t)(t * B_ + mm) * H_ + nn] = hb;
              if (t == S_ - 1) hfin[B_ * H_ + mm * H_ + nn] = hn;
            }
          }
        }
      }
    }
    gbar(bar_flags, bar_gen, bidx++);
  }
}

// ---------------------------------- host launcher ---------------------------------------
extern "C" void kernel_launch(void* const* d_in, const int* in_sizes, int n_in,
                              void* d_out, int out_size, void* d_ws, size_t ws_size,
                              hipStream_t stream) {
  const int*   inputs      = (const int*)d_in[0];
  const float* init_hidden = (const float*)d_in[1];
  const float* emb         = (const float*)d_in[2];
  const float* Wr0 = (const float*)d_in[3];
  const float* Wz0 = (const float*)d_in[4];
  const float* Wh0 = (const float*)d_in[5];
  const float* br0 = (const float*)d_in[6];
  const float* bz0 = (const float*)d_in[7];
  const float* bh0 = (const float*)d_in[8];
  const float* Wr1 = (const float*)d_in[9];
  const float* Wz1 = (const float*)d_in[10];
  const float* Wh1 = (const float*)d_in[11];
  const float* br1 = (const float*)d_in[12];
  const float* bz1 = (const float*)d_in[13];
  const float* bh1 = (const float*)d_in[14];
  const float* Wfc0 = (const float*)d_in[15];
  const float* bfc0 = (const float*)d_in[16];
  const float* Wout = (const float*)d_in[17];
  const float* bout = (const float*)d_in[18];
  float* out = (float*)d_out;

  // -------- workspace layout --------
  char* ws = (char*)d_ws;
  size_t off = 0;
  auto alloc = [&](size_t bytes) -> char* {
    char* p = ws + off;
    off = (off + bytes + 255) & ~(size_t)255;
    return p;
  };
  int* bar = (int*)alloc(2048);  // flags[256] @0, gen @ +256 ints
  __hip_bfloat16* W0xT  = (__hip_bfloat16*)alloc((size_t)3072 * E_ * 2);
  __hip_bfloat16* W0hT  = (__hip_bfloat16*)alloc((size_t)3072 * H_ * 2);
  __hip_bfloat16* WfcT  = (__hip_bfloat16*)alloc((size_t)H_ * H_ * 2);
  __hip_bfloat16* W1xT  = (__hip_bfloat16*)alloc((size_t)3072 * H_ * 2);
  __hip_bfloat16* W1hT  = (__hip_bfloat16*)alloc((size_t)3072 * H_ * 2);
  __hip_bfloat16* WoutT = (__hip_bfloat16*)alloc((size_t)VPAD * H_ * 2);
  float* b0cat = (float*)alloc(3072 * 4);
  float* b1cat = (float*)alloc(3072 * 4);
  __hip_bfloat16* X0    = (__hip_bfloat16*)alloc((size_t)M_ * E_ * 2);
  float* G              = (float*)alloc((size_t)M_ * 3072 * 4);
  __hip_bfloat16* Hseq1 = (__hip_bfloat16*)alloc((size_t)M_ * H_ * 2);
  float* g1buf          = (float*)alloc((size_t)B_ * 3072 * 4);
  __hip_bfloat16* x1b = (__hip_bfloat16*)alloc((size_t)B_ * H_ * 2);
  __hip_bfloat16* hb0 = (__hip_bfloat16*)alloc((size_t)B_ * H_ * 2);
  __hip_bfloat16* hb1 = (__hip_bfloat16*)alloc((size_t)B_ * H_ * 2);
  __hip_bfloat16* rh0 = (__hip_bfloat16*)alloc((size_t)B_ * H_ * 2);
  __hip_bfloat16* rh1 = (__hip_bfloat16*)alloc((size_t)B_ * H_ * 2);
  (void)ws_size; (void)n_in; (void)in_sizes; (void)out_size;

  // zero the barrier state (workspace is poisoned 0xAA before every launch)
  hipMemsetAsync(bar, 0, 2048, stream);

  // -------- prep: biases, transposed bf16 weights, embedding --------
  hipLaunchKernelGGL(bias_concat, dim3(12), dim3(256), 0, stream,
                     br0, bz0, bh0, br1, bz1, bh1, b0cat, b1cat);

  auto tp = [&](const float* src, __hip_bfloat16* dst, int R, int C) {
    hipLaunchKernelGGL(transpose_cast, dim3((C + 31) / 32, (R + 31) / 32), dim3(256), 0,
                       stream, src, dst, R, C);
  };
  // layer 0 x-part [E,H] -> [3H, E]
  tp(Wr0,            W0xT,                E_, H_);
  tp(Wz0,            W0xT + 1024 * E_,    E_, H_);
  tp(Wh0,            W0xT + 2048 * E_,    E_, H_);
  // layer 0 h-part
  tp(Wr0 + (size_t)E_ * H_, W0hT,               H_, H_);
  tp(Wz0 + (size_t)E_ * H_, W0hT + 1024 * H_,   H_, H_);
  tp(Wh0 + (size_t)E_ * H_, W0hT + 2048 * H_,   H_, H_);
  // fc
  tp(Wfc0, WfcT, H_, H_);
  // layer 1 x-part
  tp(Wr1,            W1xT,                H_, H_);
  tp(Wz1,            W1xT + 1024 * H_,    H_, H_);
  tp(Wh1,            W1xT + 2048 * H_,    H_, H_);
  // layer 1 h-part
  tp(Wr1 + (size_t)H_ * H_, W1hT,               H_, H_);
  tp(Wz1 + (size_t)H_ * H_, W1hT + 1024 * H_,   H_, H_);
  tp(Wh1 + (size_t)H_ * H_, W1hT + 2048 * H_,   H_, H_);
  // out projection [H,V] -> [Vpad, H] (rows >= V left as poison, guarded at GEMM store)
  tp(Wout, WoutT, H_, V_);

  hipLaunchKernelGGL(embed_cast, dim3(M_ * (E_ / 4) / 256), dim3(256), 0, stream,
                     inputs, emb, X0);

  // -------- G0 = X0 @ W0x + b0cat  (fp32 [4096,3072]) --------
  hipLaunchKernelGGL(gemm_bf16, dim3(3072 / 64, M_ / 64), dim3(256), 0, stream,
                     X0, W0xT, b0cat, (void*)G, M_, 3072, E_, 0, 0);

  // -------- fused pipeline: L0 recurrence + fc + G1 + L1 recurrence --------
  {
    const float* Gp = G;
    const __hip_bfloat16* w0h = W0hT; const __hip_bfloat16* wfc = WfcT;
    const __hip_bfloat16* w1x = W1xT; const __hip_bfloat16* w1h = W1hT;
    const float* bfcp = bfc0; const float* b1p = b1cat;
    const float* inith = init_hidden;
    __hip_bfloat16* h0p = hb0; __hip_bfloat16* rh0p = rh0;
    __hip_bfloat16* h1p = hb1; __hip_bfloat16* rh1p = rh1;
    __hip_bfloat16* x1p = x1b; float* g1p = g1buf;
    __hip_bfloat16* Hs1 = Hseq1;
    float* hfin = out + (size_t)M_ * V_;   // h_final (layer 0 at +0, layer 1 at +B*H)
    int* fl = bar; int* gn = bar + 256;
    void* kargs[] = {(void*)&Gp, (void*)&w0h, (void*)&wfc, (void*)&w1x, (void*)&w1h,
                     (void*)&bfcp, (void*)&b1p, (void*)&inith,
                     (void*)&h0p, (void*)&rh0p, (void*)&h1p, (void*)&rh1p,
                     (void*)&x1p, (void*)&g1p, (void*)&Hs1, (void*)&hfin,
                     (void*)&fl, (void*)&gn};
    hipLaunchCooperativeKernel((const void*)gru_fused, dim3(NBLK), dim3(256),
                               kargs, 0, stream);
  }

  // -------- logits = Hseq1 @ Wout + bout  (fp32 [4096,10000] straight into d_out) -------
  hipLaunchKernelGGL(gemm_bf16, dim3(VPAD / 64, M_ / 64), dim3(256), 0, stream,
                     Hseq1, WoutT, bout, (void*)out, M_, V_, H_, 0, 0);
}

// Round 5
// 2392.673 us; speedup vs baseline: 1.8455x; 1.0553x over previous
//
#include <hip/hip_runtime.h>
#include <hip/hip_bf16.h>

typedef __attribute__((ext_vector_type(8))) short short8;
typedef __attribute__((ext_vector_type(4))) float f32x4;

#define S_ 64
#define B_ 64
#define H_ 1024
#define E_ 512
#define V_ 10000
#define M_ 4096          // S_*B_
#define VPAD 10048       // V rounded up to 64
#define NBLK 256         // 4 gangs x 64 blocks
#define BH (B_ * H_)

__device__ __forceinline__ float sigmoidf_(float x) {
  return 1.0f / (1.0f + __expf(-x));
}

// ---- decentralized producer/consumer sync ---------------------------------------------
// prog[bid] = 1 after init, k+2 after tick k. Monotonic, never reset.
// publish(): __syncthreads (drains all waves' vmem via compiler's pre-barrier waitcnt),
// then thread0 release-stores (release => buffer_wbl2 => all the block's prior stores are
// globally visible BEFORE the flag is). r4 lesson: vmcnt(0) alone is NOT visibility.
__device__ __forceinline__ void publish(int* prog, int bid, int val, bool rel) {
  __syncthreads();
  if (threadIdx.x == 0) {
    if (rel) __hip_atomic_store(&prog[bid], val, __ATOMIC_RELEASE, __HIP_MEMORY_SCOPE_AGENT);
    else     __hip_atomic_store(&prog[bid], val, __ATOMIC_RELAXED, __HIP_MEMORY_SCOPE_AGENT);
  }
}
// wait on one or two 64-flag sets (wave0: one flag per lane, relaxed polls), then ONE
// acquire fence (buffer_inv: L1+L2 invalidate so subsequent normal loads see fresh data).
__device__ __forceinline__ void wait_two(int* prog, int b0, int r0, int b1, int r1) {
  if (threadIdx.x < 64) {
    int l = threadIdx.x;
    for (;;) {
      bool ok = __hip_atomic_load(&prog[b0 + l], __ATOMIC_RELAXED,
                                  __HIP_MEMORY_SCOPE_AGENT) >= r0;
      if (b1 >= 0)
        ok &= __hip_atomic_load(&prog[b1 + l], __ATOMIC_RELAXED,
                                __HIP_MEMORY_SCOPE_AGENT) >= r1;
      if (__all(ok)) break;
      __builtin_amdgcn_s_sleep(1);
    }
    __builtin_amdgcn_fence(__ATOMIC_ACQUIRE, "agent");
  }
  __syncthreads();
}

// ---------------- bias concat: b0cat = [br0,bz0,bh0], b1cat = [br1,bz1,bh1] -------------
__global__ void bias_concat(const float* br0, const float* bz0, const float* bh0,
                            const float* br1, const float* bz1, const float* bh1,
                            float* b0cat, float* b1cat) {
  int i = blockIdx.x * 256 + threadIdx.x;   // 0..3071
  if (i >= 3072) return;
  if (i < 1024)       { b0cat[i] = br0[i];        b1cat[i] = br1[i]; }
  else if (i < 2048)  { b0cat[i] = bz0[i - 1024]; b1cat[i] = bz1[i - 1024]; }
  else                { b0cat[i] = bh0[i - 2048]; b1cat[i] = bh1[i - 2048]; }
}

// ---------------- transpose + cast: dst[c*R + r] = bf16(src[r*C + c]) -------------------
__global__ void transpose_cast(const float* __restrict__ src, __hip_bfloat16* __restrict__ dst,
                               int R, int C) {
  __shared__ float tile[32][33];
  int c0 = blockIdx.x * 32, r0 = blockIdx.y * 32;
  int tx = threadIdx.x & 31, ty = threadIdx.x >> 5;   // 32 x 8
#pragma unroll
  for (int i = 0; i < 4; ++i) {
    int r = r0 + ty + i * 8;
    int c = c0 + tx;
    if (r < R && c < C) tile[ty + i * 8][tx] = src[(size_t)r * C + c];
  }
  __syncthreads();
#pragma unroll
  for (int i = 0; i < 4; ++i) {
    int c = c0 + ty + i * 8;
    int r = r0 + tx;
    if (c < C && r < R) dst[(size_t)c * R + r] = __float2bfloat16(tile[tx][ty + i * 8]);
  }
}

// ---------------- embedding gather + cast to bf16: X0[i][e] = emb[tok[i]][e] ------------
__global__ void embed_cast(const int* __restrict__ inputs, const float* __restrict__ emb,
                           __hip_bfloat16* __restrict__ X0) {
  int idx = blockIdx.x * 256 + threadIdx.x;  // over 4096 * 128 float4 groups
  int i = idx >> 7;
  int e4 = idx & 127;
  int tok = inputs[i];
  const float4* src = (const float4*)(emb + (size_t)tok * E_);
  float4 v = src[e4];
  __hip_bfloat16* dst = X0 + (size_t)i * E_ + e4 * 4;
  dst[0] = __float2bfloat16(v.x);
  dst[1] = __float2bfloat16(v.y);
  dst[2] = __float2bfloat16(v.z);
  dst[3] = __float2bfloat16(v.w);
}

// ---------------- generic bf16 MFMA GEMM: C = act(A[M,K] @ BT[N,K]^T + bias) ------------
// grid = (ceil(N/64), M/64), block = 256 (4 waves, each a 32x32 quadrant of the 64x64 tile)
__global__ __launch_bounds__(256) void gemm_bf16(
    const __hip_bfloat16* __restrict__ A, const __hip_bfloat16* __restrict__ BT,
    const float* __restrict__ bias, void* __restrict__ C,
    int M, int N, int K, int act, int out_bf16) {
  __shared__ unsigned short Al[64 * 72];
  __shared__ unsigned short Bl[64 * 72];
  const int m0 = blockIdx.y * 64, n0 = blockIdx.x * 64;
  const int tid = threadIdx.x;
  const int wave = tid >> 6, lane = tid & 63;
  const int quad = lane >> 4, lr = lane & 15;
  const int wm = (wave >> 1) * 32, wn = (wave & 1) * 32;
  const int srow = tid >> 2, scol = (tid & 3) << 4;

  f32x4 acc[2][2];
#pragma unroll
  for (int a = 0; a < 2; ++a)
#pragma unroll
    for (int b = 0; b < 2; ++b) acc[a][b] = (f32x4){0.f, 0.f, 0.f, 0.f};

  const __hip_bfloat16* Ag = A + (size_t)(m0 + srow) * K + scol;
  const __hip_bfloat16* Bg = BT + (size_t)(n0 + srow) * K + scol;

  for (int kb = 0; kb < K; kb += 64) {
    short8 a0 = *(const short8*)(Ag + kb);
    short8 a1 = *(const short8*)(Ag + kb + 8);
    short8 b0 = *(const short8*)(Bg + kb);
    short8 b1 = *(const short8*)(Bg + kb + 8);
    *(short8*)&Al[srow * 72 + scol] = a0;
    *(short8*)&Al[srow * 72 + scol + 8] = a1;
    *(short8*)&Bl[srow * 72 + scol] = b0;
    *(short8*)&Bl[srow * 72 + scol + 8] = b1;
    __syncthreads();
#pragma unroll
    for (int k2 = 0; k2 < 64; k2 += 32) {
      short8 af0 = *(const short8*)&Al[(wm + lr) * 72 + k2 + quad * 8];
      short8 af1 = *(const short8*)&Al[(wm + 16 + lr) * 72 + k2 + quad * 8];
      short8 bf0 = *(const short8*)&Bl[(wn + lr) * 72 + k2 + quad * 8];
      short8 bf1 = *(const short8*)&Bl[(wn + 16 + lr) * 72 + k2 + quad * 8];
      acc[0][0] = __builtin_amdgcn_mfma_f32_16x16x32_bf16(af0, bf0, acc[0][0], 0, 0, 0);
      acc[0][1] = __builtin_amdgcn_mfma_f32_16x16x32_bf16(af0, bf1, acc[0][1], 0, 0, 0);
      acc[1][0] = __builtin_amdgcn_mfma_f32_16x16x32_bf16(af1, bf0, acc[1][0], 0, 0, 0);
      acc[1][1] = __builtin_amdgcn_mfma_f32_16x16x32_bf16(af1, bf1, acc[1][1], 0, 0, 0);
    }
    __syncthreads();
  }

#pragma unroll
  for (int mi = 0; mi < 2; ++mi)
#pragma unroll
    for (int ni = 0; ni < 2; ++ni) {
      int n = n0 + wn + ni * 16 + lr;
      if (n >= N) continue;
      float bv = bias ? bias[n] : 0.f;
#pragma unroll
      for (int r = 0; r < 4; ++r) {
        int m = m0 + wm + mi * 16 + quad * 4 + r;
        float v = acc[mi][ni][r] + bv;
        if (act) v = sigmoidf_(v);
        if (out_bf16) ((__hip_bfloat16*)C)[(size_t)m * N + n] = __float2bfloat16(v);
        else          ((float*)C)[(size_t)m * N + n] = v;
      }
    }
}

// ---------------- fused 2-layer GRU pipeline (decentralized sync) -----------------------
// 4 gangs x 64 blocks on a 2-ticks-per-step schedule (as r3), but NO global barrier:
//   gang 0 (prog[  0.. 63]): L0 phase A at tick 2t, phase B at 2t+1 -> h0b[t&1]
//   gang 1 (prog[ 64..127]): x1_t = sigmoid(h0_t@Wfc+bfc) at 2t+2   -> x1b[t&1]
//   gang 2 (prog[128..191]): g1_t = x1_t@W1x+b1cat at 2t+3          -> g1buf[t&1]
//   gang 3 (prog[192..255]): L1 phase A at 2t+4, phase B at 2t+5    -> h1b, Hseq1
// Sync per active tick k: wait forward-producer gang >= k+1 (finished k-1) and/or
// backpressure consumer gang >= k-1 (finished k-3; parity buffers give 3-tick slack);
// own-gang >= k+1 where intra-gang buffers (rh0/rh1/h0b/h1b) are involved.
// Every block publishes prog = k+2 after every tick (release when it stored data).
__global__ __launch_bounds__(256, 1) void gru_fused(
    const float* __restrict__ G0,
    const __hip_bfloat16* __restrict__ W0hT, const __hip_bfloat16* __restrict__ WfcT,
    const __hip_bfloat16* __restrict__ W1xT, const __hip_bfloat16* __restrict__ W1hT,
    const float* __restrict__ bfc, const float* __restrict__ b1cat,
    const float* __restrict__ init_h,
    __hip_bfloat16* __restrict__ h0b, __hip_bfloat16* __restrict__ rh0,
    __hip_bfloat16* __restrict__ h1b, __hip_bfloat16* __restrict__ rh1,
    __hip_bfloat16* __restrict__ x1b, float* __restrict__ g1buf,
    __hip_bfloat16* __restrict__ Hseq1, float* __restrict__ hfin,
    int* __restrict__ prog) {
  __shared__ unsigned short Wl[48 * 1032];

  const int bid = blockIdx.x;
  const int gang = bid >> 6;      // 0:L0  1:FC  2:G1  3:L1
  const int gid = bid & 63;
  const int tid = threadIdx.x;
  const int wave = tid >> 6, lane = tid & 63;
  const int quad = lane >> 4, lr = lane & 15;

  // ---- stage this gang's weight slice into LDS (once) ----
  if (gang == 0 || gang == 3) {
    const __hip_bfloat16* WT = (gang == 0) ? W0hT : W1hT;
    const int nb = gid * 16;
    for (int c = tid; c < 48 * 128; c += 256) {
      int row = c >> 7, col = c & 127;
      int seg = row >> 4, srow = row & 15;
      short8 v = *(const short8*)(WT + (size_t)(seg * 1024 + nb + srow) * H_ + col * 8);
      *(short8*)&Wl[row * 1032 + col * 8] = v;
    }
  } else if (gang == 1) {
    const int nb = gid * 16;
    for (int c = tid; c < 16 * 128; c += 256) {
      int row = c >> 7, col = c & 127;
      short8 v = *(const short8*)(WfcT + (size_t)(nb + row) * H_ + col * 8);
      *(short8*)&Wl[row * 1032 + col * 8] = v;
    }
  } else {
    const int nb = gid * 48;
    for (int c = tid; c < 48 * 128; c += 256) {
      int row = c >> 7, col = c & 127;
      short8 v = *(const short8*)(W1xT + (size_t)(nb + row) * H_ + col * 8);
      *(short8*)&Wl[row * 1032 + col * 8] = v;
    }
  }

  // ---- per-gang persistent register state + init publishes ----
  float hreg[4], zreg[4], ghp[4];
  float bias0 = 0.f, bias1 = 0.f, bias2 = 0.f;
  if (gang == 0 || gang == 3) {
    const float* ih = init_h + (gang == 3 ? BH : 0);
    // init h (= h_{-1}) goes to parity 1 for layer 0 (A of t reads h0b[(t+1)&1]);
    // layer 1's h1b is flat (intra-gang only).
    __hip_bfloat16* hb = (gang == 0) ? (h0b + BH) : h1b;
    const int nb = gid * 16;
#pragma unroll
    for (int r = 0; r < 4; ++r) {
      int mm = wave * 16 + quad * 4 + r;
      float v = ih[mm * H_ + nb + lr];
      hreg[r] = v; zreg[r] = 0.f; ghp[r] = 0.f;
      hb[mm * H_ + nb + lr] = __float2bfloat16(v);
    }
  } else if (gang == 1) {
    bias0 = bfc[gid * 16 + lr];
  } else {
    const int nb = gid * 48;
    bias0 = b1cat[nb + lr];
    bias1 = b1cat[nb + 16 + lr];
    bias2 = b1cat[nb + 32 + lr];
  }
  publish(prog, bid, 1, gang == 0 || gang == 3);

  for (int k = 0; k < 132; ++k) {
    bool active = false;
    if (gang == 0) {
      if (k < 128) {
        active = true;
        const int nb = gid * 16;
        const int am = wave * 16 + lr;
        const int t = k >> 1;
        if (!(k & 1)) {
          // ---- L0 phase A: needs own gang finished k-1 (h0b[(t+1)&1] = h_{t-1}) ----
          wait_two(prog, 0, k + 1, -1, 0);
          float g0v[4], g1v[4];
#pragma unroll
          for (int r = 0; r < 4; ++r) {
            int mm = wave * 16 + quad * 4 + r;
            const float* gp = G0 + (size_t)(t * B_ + mm) * 3072 + nb + lr;
            g0v[r] = gp[0]; g1v[r] = gp[1024]; ghp[r] = gp[2048];
          }
          const __hip_bfloat16* ap = h0b + (size_t)((t + 1) & 1) * BH + (size_t)am * H_ + quad * 8;
          short8 areg[32];
#pragma unroll
          for (int kk = 0; kk < 32; ++kk) areg[kk] = *(const short8*)(ap + kk * 32);
          f32x4 acc0 = (f32x4){0.f, 0.f, 0.f, 0.f};
          f32x4 acc1 = (f32x4){0.f, 0.f, 0.f, 0.f};
#pragma unroll
          for (int kk = 0; kk < 32; ++kk) {
            short8 b0 = *(const short8*)&Wl[lr * 1032 + quad * 8 + kk * 32];
            short8 b1 = *(const short8*)&Wl[(16 + lr) * 1032 + quad * 8 + kk * 32];
            acc0 = __builtin_amdgcn_mfma_f32_16x16x32_bf16(areg[kk], b0, acc0, 0, 0, 0);
            acc1 = __builtin_amdgcn_mfma_f32_16x16x32_bf16(areg[kk], b1, acc1, 0, 0, 0);
          }
#pragma unroll
          for (int r = 0; r < 4; ++r) {
            int mm = wave * 16 + quad * 4 + r;
            float rv = sigmoidf_(acc0[r] + g0v[r]);
            zreg[r] = sigmoidf_(acc1[r] + g1v[r]);
            rh0[mm * H_ + nb + lr] = __float2bfloat16(rv * hreg[r]);
          }
        } else {
          // ---- L0 phase B: own finished k-1 (rh0); gang1 finished k-3 (h0b[t&1] free) ----
          wait_two(prog, 0, k + 1, 64, k - 1);
          const __hip_bfloat16* ap = rh0 + (size_t)am * H_ + quad * 8;
          short8 areg[32];
#pragma unroll
          for (int kk = 0; kk < 32; ++kk) areg[kk] = *(const short8*)(ap + kk * 32);
          f32x4 acc = (f32x4){0.f, 0.f, 0.f, 0.f};
#pragma unroll
          for (int kk = 0; kk < 32; ++kk) {
            short8 b = *(const short8*)&Wl[(32 + lr) * 1032 + quad * 8 + kk * 32];
            acc = __builtin_amdgcn_mfma_f32_16x16x32_bf16(areg[kk], b, acc, 0, 0, 0);
          }
          __hip_bfloat16* hw = h0b + (size_t)(t & 1) * BH;
#pragma unroll
          for (int r = 0; r < 4; ++r) {
            int mm = wave * 16 + quad * 4 + r;
            int nn = nb + lr;
            float hh = sigmoidf_(acc[r] + ghp[r]);
            float hn = hreg[r] + zreg[r] * (hh - hreg[r]);
            hreg[r] = hn;
            hw[mm * H_ + nn] = __float2bfloat16(hn);
            if (t == S_ - 1) hfin[mm * H_ + nn] = hn;
          }
        }
      }
    } else if (gang == 1) {
      // ---- FC at even ticks 2..128: gang0 finished k-1; gang2 finished k-3 ----
      if (!(k & 1) && k >= 2 && k <= 128) {
        active = true;
        wait_two(prog, 0, k + 1, 128, k - 1);
        const int t = (k - 2) >> 1;
        const int nb = gid * 16;
        const int am = wave * 16 + lr;
        const __hip_bfloat16* ap = h0b + (size_t)(t & 1) * BH + (size_t)am * H_ + quad * 8;
        short8 areg[32];
#pragma unroll
        for (int kk = 0; kk < 32; ++kk) areg[kk] = *(const short8*)(ap + kk * 32);
        f32x4 acc = (f32x4){0.f, 0.f, 0.f, 0.f};
#pragma unroll
        for (int kk = 0; kk < 32; ++kk) {
          short8 b = *(const short8*)&Wl[lr * 1032 + quad * 8 + kk * 32];
          acc = __builtin_amdgcn_mfma_f32_16x16x32_bf16(areg[kk], b, acc, 0, 0, 0);
        }
        __hip_bfloat16* xw = x1b + (size_t)(t & 1) * BH;
#pragma unroll
        for (int r = 0; r < 4; ++r) {
          int mm = wave * 16 + quad * 4 + r;
          float v = sigmoidf_(acc[r] + bias0);
          xw[mm * H_ + nb + lr] = __float2bfloat16(v);
        }
      }
    } else if (gang == 2) {
      // ---- G1 at odd ticks 3..129: gang1 finished k-1; gang3 finished k-3 ----
      if ((k & 1) && k >= 3 && k <= 129) {
        active = true;
        wait_two(prog, 64, k + 1, 192, k - 1);
        const int t = (k - 3) >> 1;
        const int nb = gid * 48;
        const int am = wave * 16 + lr;
        const __hip_bfloat16* ap = x1b + (size_t)(t & 1) * BH + (size_t)am * H_ + quad * 8;
        short8 areg[32];
#pragma unroll
        for (int kk = 0; kk < 32; ++kk) areg[kk] = *(const short8*)(ap + kk * 32);
        f32x4 a0 = (f32x4){0.f, 0.f, 0.f, 0.f};
        f32x4 a1 = (f32x4){0.f, 0.f, 0.f, 0.f};
        f32x4 a2 = (f32x4){0.f, 0.f, 0.f, 0.f};
#pragma unroll
        for (int kk = 0; kk < 32; ++kk) {
          short8 b0 = *(const short8*)&Wl[lr * 1032 + quad * 8 + kk * 32];
          short8 b1 = *(const short8*)&Wl[(16 + lr) * 1032 + quad * 8 + kk * 32];
          short8 b2 = *(const short8*)&Wl[(32 + lr) * 1032 + quad * 8 + kk * 32];
          a0 = __builtin_amdgcn_mfma_f32_16x16x32_bf16(areg[kk], b0, a0, 0, 0, 0);
          a1 = __builtin_amdgcn_mfma_f32_16x16x32_bf16(areg[kk], b1, a1, 0, 0, 0);
          a2 = __builtin_amdgcn_mfma_f32_16x16x32_bf16(areg[kk], b2, a2, 0, 0, 0);
        }
        float* gw = g1buf + (size_t)(t & 1) * (B_ * 3072);
#pragma unroll
        for (int r = 0; r < 4; ++r) {
          int mm = wave * 16 + quad * 4 + r;
          float* gp = gw + (size_t)mm * 3072 + nb + lr;
          gp[0]  = a0[r] + bias0;
          gp[16] = a1[r] + bias1;
          gp[32] = a2[r] + bias2;
        }
      }
    } else {
      // ---- L1 recurrence ----
      const int nb = gid * 16;
      const int am = wave * 16 + lr;
      if (!(k & 1)) {
        if (k >= 4 && k <= 130) {
          active = true;
          // phase A: gang2 finished k-1 (g1buf); own finished k-1 (h1b)
          wait_two(prog, 128, k + 1, 192, k + 1);
          const int t = (k - 4) >> 1;
          const float* gr = g1buf + (size_t)(t & 1) * (B_ * 3072);
          float g0v[4], g1v[4];
#pragma unroll
          for (int r = 0; r < 4; ++r) {
            int mm = wave * 16 + quad * 4 + r;
            const float* gp = gr + (size_t)mm * 3072 + nb + lr;
            g0v[r] = gp[0]; g1v[r] = gp[1024]; ghp[r] = gp[2048];
          }
          const __hip_bfloat16* ap = h1b + (size_t)am * H_ + quad * 8;
          short8 areg[32];
#pragma unroll
          for (int kk = 0; kk < 32; ++kk) areg[kk] = *(const short8*)(ap + kk * 32);
          f32x4 acc0 = (f32x4){0.f, 0.f, 0.f, 0.f};
          f32x4 acc1 = (f32x4){0.f, 0.f, 0.f, 0.f};
#pragma unroll
          for (int kk = 0; kk < 32; ++kk) {
            short8 b0 = *(const short8*)&Wl[lr * 1032 + quad * 8 + kk * 32];
            short8 b1 = *(const short8*)&Wl[(16 + lr) * 1032 + quad * 8 + kk * 32];
            acc0 = __builtin_amdgcn_mfma_f32_16x16x32_bf16(areg[kk], b0, acc0, 0, 0, 0);
            acc1 = __builtin_amdgcn_mfma_f32_16x16x32_bf16(areg[kk], b1, acc1, 0, 0, 0);
          }
#pragma unroll
          for (int r = 0; r < 4; ++r) {
            int mm = wave * 16 + quad * 4 + r;
            float rv = sigmoidf_(acc0[r] + g0v[r]);
            zreg[r] = sigmoidf_(acc1[r] + g1v[r]);
            rh1[mm * H_ + nb + lr] = __float2bfloat16(rv * hreg[r]);
          }
        }
      } else {
        if (k >= 5 && k <= 131) {
          active = true;
          // phase B: own finished k-1 (rh1)
          wait_two(prog, 192, k + 1, -1, 0);
          const int t = (k - 5) >> 1;
          const __hip_bfloat16* ap = rh1 + (size_t)am * H_ + quad * 8;
          short8 areg[32];
#pragma unroll
          for (int kk = 0; kk < 32; ++kk) areg[kk] = *(const short8*)(ap + kk * 32);
          f32x4 acc = (f32x4){0.f, 0.f, 0.f, 0.f};
#pragma unroll
          for (int kk = 0; kk < 32; ++kk) {
            short8 b = *(const short8*)&Wl[(32 + lr) * 1032 + quad * 8 + kk * 32];
            acc = __builtin_amdgcn_mfma_f32_16x16x32_bf16(areg[kk], b, acc, 0, 0, 0);
          }
#pragma unroll
          for (int r = 0; r < 4; ++r) {
            int mm = wave * 16 + quad * 4 + r;
            int nn = nb + lr;
            float hh = sigmoidf_(acc[r] + ghp[r]);
            float hn = hreg[r] + zreg[r] * (hh - hreg[r]);
            hreg[r] = hn;
            __hip_bfloat16 hb = __float2bfloat16(hn);
            h1b[mm * H_ + nn] = hb;
            Hseq1[(size_t)(t * B_ + mm) * H_ + nn] = hb;
            if (t == S_ - 1) hfin[BH + mm * H_ + nn] = hn;
          }
        }
      }
    }
    publish(prog, bid, k + 2, active);
  }
}

// ---------------------------------- host launcher ---------------------------------------
extern "C" void kernel_launch(void* const* d_in, const int* in_sizes, int n_in,
                              void* d_out, int out_size, void* d_ws, size_t ws_size,
                              hipStream_t stream) {
  const int*   inputs      = (const int*)d_in[0];
  const float* init_hidden = (const float*)d_in[1];
  const float* emb         = (const float*)d_in[2];
  const float* Wr0 = (const float*)d_in[3];
  const float* Wz0 = (const float*)d_in[4];
  const float* Wh0 = (const float*)d_in[5];
  const float* br0 = (const float*)d_in[6];
  const float* bz0 = (const float*)d_in[7];
  const float* bh0 = (const float*)d_in[8];
  const float* Wr1 = (const float*)d_in[9];
  const float* Wz1 = (const float*)d_in[10];
  const float* Wh1 = (const float*)d_in[11];
  const float* br1 = (const float*)d_in[12];
  const float* bz1 = (const float*)d_in[13];
  const float* bh1 = (const float*)d_in[14];
  const float* Wfc0 = (const float*)d_in[15];
  const float* bfc0 = (const float*)d_in[16];
  const float* Wout = (const float*)d_in[17];
  const float* bout = (const float*)d_in[18];
  float* out = (float*)d_out;

  // -------- workspace layout --------
  char* ws = (char*)d_ws;
  size_t off = 0;
  auto alloc = [&](size_t bytes) -> char* {
    char* p = ws + off;
    off = (off + bytes + 255) & ~(size_t)255;
    return p;
  };
  int* prog = (int*)alloc(2048);  // prog[256]
  __hip_bfloat16* W0xT  = (__hip_bfloat16*)alloc((size_t)3072 * E_ * 2);
  __hip_bfloat16* W0hT  = (__hip_bfloat16*)alloc((size_t)3072 * H_ * 2);
  __hip_bfloat16* WfcT  = (__hip_bfloat16*)alloc((size_t)H_ * H_ * 2);
  __hip_bfloat16* W1xT  = (__hip_bfloat16*)alloc((size_t)3072 * H_ * 2);
  __hip_bfloat16* W1hT  = (__hip_bfloat16*)alloc((size_t)3072 * H_ * 2);
  __hip_bfloat16* WoutT = (__hip_bfloat16*)alloc((size_t)VPAD * H_ * 2);
  float* b0cat = (float*)alloc(3072 * 4);
  float* b1cat = (float*)alloc(3072 * 4);
  __hip_bfloat16* X0    = (__hip_bfloat16*)alloc((size_t)M_ * E_ * 2);
  float* G              = (float*)alloc((size_t)M_ * 3072 * 4);
  __hip_bfloat16* Hseq1 = (__hip_bfloat16*)alloc((size_t)M_ * H_ * 2);
  float* g1buf          = (float*)alloc((size_t)2 * B_ * 3072 * 4);  // parity double-buffer
  __hip_bfloat16* h0b = (__hip_bfloat16*)alloc((size_t)2 * BH * 2);  // parity
  __hip_bfloat16* x1b = (__hip_bfloat16*)alloc((size_t)2 * BH * 2);  // parity
  __hip_bfloat16* h1b = (__hip_bfloat16*)alloc((size_t)BH * 2);
  __hip_bfloat16* rh0 = (__hip_bfloat16*)alloc((size_t)BH * 2);
  __hip_bfloat16* rh1 = (__hip_bfloat16*)alloc((size_t)BH * 2);
  (void)ws_size; (void)n_in; (void)in_sizes; (void)out_size;

  // zero the progress flags (workspace is poisoned 0xAA before every launch)
  hipMemsetAsync(prog, 0, 2048, stream);

  // -------- prep: biases, transposed bf16 weights, embedding --------
  hipLaunchKernelGGL(bias_concat, dim3(12), dim3(256), 0, stream,
                     br0, bz0, bh0, br1, bz1, bh1, b0cat, b1cat);

  auto tp = [&](const float* src, __hip_bfloat16* dst, int R, int C) {
    hipLaunchKernelGGL(transpose_cast, dim3((C + 31) / 32, (R + 31) / 32), dim3(256), 0,
                       stream, src, dst, R, C);
  };
  // layer 0 x-part [E,H] -> [3H, E]
  tp(Wr0,            W0xT,                E_, H_);
  tp(Wz0,            W0xT + 1024 * E_,    E_, H_);
  tp(Wh0,            W0xT + 2048 * E_,    E_, H_);
  // layer 0 h-part
  tp(Wr0 + (size_t)E_ * H_, W0hT,               H_, H_);
  tp(Wz0 + (size_t)E_ * H_, W0hT + 1024 * H_,   H_, H_);
  tp(Wh0 + (size_t)E_ * H_, W0hT + 2048 * H_,   H_, H_);
  // fc
  tp(Wfc0, WfcT, H_, H_);
  // layer 1 x-part
  tp(Wr1,            W1xT,                H_, H_);
  tp(Wz1,            W1xT + 1024 * H_,    H_, H_);
  tp(Wh1,            W1xT + 2048 * H_,    H_, H_);
  // layer 1 h-part
  tp(Wr1 + (size_t)H_ * H_, W1hT,               H_, H_);
  tp(Wz1 + (size_t)H_ * H_, W1hT + 1024 * H_,   H_, H_);
  tp(Wh1 + (size_t)H_ * H_, W1hT + 2048 * H_,   H_, H_);
  // out projection [H,V] -> [Vpad, H] (rows >= V left as poison, guarded at GEMM store)
  tp(Wout, WoutT, H_, V_);

  hipLaunchKernelGGL(embed_cast, dim3(M_ * (E_ / 4) / 256), dim3(256), 0, stream,
                     inputs, emb, X0);

  // -------- G0 = X0 @ W0x + b0cat  (fp32 [4096,3072]) --------
  hipLaunchKernelGGL(gemm_bf16, dim3(3072 / 64, M_ / 64), dim3(256), 0, stream,
                     X0, W0xT, b0cat, (void*)G, M_, 3072, E_, 0, 0);

  // -------- fused pipeline: L0 recurrence + fc + G1 + L1 recurrence --------
  {
    const float* Gp = G;
    const __hip_bfloat16* w0h = W0hT; const __hip_bfloat16* wfc = WfcT;
    const __hip_bfloat16* w1x = W1xT; const __hip_bfloat16* w1h = W1hT;
    const float* bfcp = bfc0; const float* b1p = b1cat;
    const float* inith = init_hidden;
    __hip_bfloat16* h0p = h0b; __hip_bfloat16* rh0p = rh0;
    __hip_bfloat16* h1p = h1b; __hip_bfloat16* rh1p = rh1;
    __hip_bfloat16* x1p = x1b; float* g1p = g1buf;
    __hip_bfloat16* Hs1 = Hseq1;
    float* hfin = out + (size_t)M_ * V_;   // h_final (layer 0 at +0, layer 1 at +B*H)
    int* pg = prog;
    void* kargs[] = {(void*)&Gp, (void*)&w0h, (void*)&wfc, (void*)&w1x, (void*)&w1h,
                     (void*)&bfcp, (void*)&b1p, (void*)&inith,
                     (void*)&h0p, (void*)&rh0p, (void*)&h1p, (void*)&rh1p,
                     (void*)&x1p, (void*)&g1p, (void*)&Hs1, (void*)&hfin,
                     (void*)&pg};
    hipLaunchCooperativeKernel((const void*)gru_fused, dim3(NBLK), dim3(256),
                               kargs, 0, stream);
  }

  // -------- logits = Hseq1 @ Wout + bout  (fp32 [4096,10000] straight into d_out) -------
  hipLaunchKernelGGL(gemm_bf16, dim3(VPAD / 64, M_ / 64), dim3(256), 0, stream,
                     Hseq1, WoutT, bout, (void*)out, M_, V_, H_, 0, 0);
}